// Round 8
// baseline (113.082 us; speedup 1.0000x reference)
//
#include <hip/hip_runtime.h>

// NMU forward: y[b,o] = prod_d( clip(M[d,o],0,1)*x[b,d] + 1-clip(M[d,o],0,1) )
// B=16384, D=256, O=32, fp32.
//
// R8: resident-M + broadcast-GLOBAL x at high occupancy.
// R7 post-mortem: broadcast ds_read_b128 costs ~12 cyc of the per-CU LDS
// port while delivering 32 B unique -> 4096 reads/CU = ~20 us = the plateau.
// Broadcast delivery must be per-instruction cheap: x comes straight from
// global (VMEM issue ~4 cyc, L1-line reuse), which needs occupancy to hide
// latency (R6 failed at 2 waves/SIMD with 212 VGPRs). So: D split in
// QUARTERS -> resident M slice = 64 d = 32 v2f = 64 VGPRs; lane=(o,dh),
// wave-pair covers D; ping-pong 2-chunk x prefetch. ~115 VGPRs ->
// __launch_bounds__(256,4), 1024 blocks = 16 waves/CU. Hot loop has ZERO
// LDS; quarter partials merge in a tiny padded-LDS epilogue.

typedef float v2f __attribute__((ext_vector_type(2)));

constexpr int D   = 256;
constexpr int O   = 32;
constexpr int QD  = 64;            // d's per quarter (resident slice)
constexpr int RPP = 8;             // rows per wave-pair
constexpr int ROWS_PB = 16;        // rows per block (2 pairs)
constexpr int PSTR = 132;          // part[] row stride, floats (pad: 4r banks)

__global__ __launch_bounds__(256, 4)
void nmu_fwd(const float* __restrict__ x, const float* __restrict__ M,
             float* __restrict__ y)
{
    __shared__ float part[ROWS_PB * PSTR];          // 8448 B
    const int tid  = threadIdx.x;
    const int lane = tid & 63;
    const int w    = tid >> 6;
    const int o    = lane & 31;                     // output column
    const int dh   = lane >> 5;                     // quarter select (low bit)
    const int pair = w >> 1;
    const int qq   = ((w & 1) << 1) | dh;           // my D-quarter 0..3
    const int rowbase = blockIdx.x * ROWS_PB + pair * RPP;

    // ---- resident clamped M quarter-slice: 64 d -> 32 v2f (64 VGPRs) ----
    const float* Mp = M + qq * QD * O + o;
    v2f m[QD / 2];
#pragma unroll
    for (int j = 0; j < QD / 2; ++j) {
        float a = Mp[(2 * j    ) * O];              // coalesced 128B/instr
        float b = Mp[(2 * j + 1) * O];
        m[j].x = __builtin_amdgcn_fmed3f(a, 0.0f, 1.0f);
        m[j].y = __builtin_amdgcn_fmed3f(b, 0.0f, 1.0f);
    }

    // ---- x broadcast pipeline: slot s=(row r, chunk c), chunk=4 f4=16 d ----
    const float4* xg = reinterpret_cast<const float4*>(x);
    auto saddr = [&](int s) {
        const int r = s >> 2, c = s & 3;
        return xg + (size_t)(rowbase + r) * (D / 4) + qq * (QD / 4) + c * 4;
    };
    float4 buf[2][4];                               // ping-pong, 32 VGPRs
    {
        const float4* a0 = saddr(0);
#pragma unroll
        for (int u = 0; u < 4; ++u) buf[0][u] = a0[u];
    }

    v2f p = {1.0f, 1.0f};
#pragma unroll 4                                    // m-indices compile-time
    for (int s = 0; s < RPP * 4; ++s) {
        if (s + 1 < RPP * 4) {                      // prefetch next chunk
            const float4* an = saddr(s + 1);
#pragma unroll
            for (int u = 0; u < 4; ++u) buf[(s + 1) & 1][u] = an[u];
        }
        v2f acc;
#pragma unroll
        for (int u = 0; u < 4; ++u) {
            const float4 xv = buf[s & 1][u];
            const int f = (s & 3) * 4 + u;          // f4 index within quarter
            v2f x01 = {xv.x - 1.0f, xv.y - 1.0f};   // t = m*(x-1)+1
            v2f x23 = {xv.z - 1.0f, xv.w - 1.0f};
            v2f t0 = m[2 * f]     * x01 + (v2f){1.0f, 1.0f};
            v2f t1 = m[2 * f + 1] * x23 + (v2f){1.0f, 1.0f};
            v2f q = t0 * t1;
            acc = (u == 0) ? q : acc * q;
        }
        p *= acc;
        if ((s & 3) == 3) {                         // row finished
            const int br = pair * RPP + (s >> 2);   // row within block
            part[br * PSTR + qq * O + o] = p.x * p.y;  // lane-linear, no conflict
            p = (v2f){1.0f, 1.0f};
        }
    }
    __syncthreads();

    // ---- merge 4 quarter-partials, store y (128 threads, f4-coalesced) ----
    if (tid < ROWS_PB * 8) {
        const int r  = tid >> 3;
        const int o4 = tid & 7;
        const float* pb = &part[r * PSTR + o4 * 4];
        float4 a = *reinterpret_cast<const float4*>(pb);
        float4 b = *reinterpret_cast<const float4*>(pb + O);
        float4 c = *reinterpret_cast<const float4*>(pb + 2 * O);
        float4 d = *reinterpret_cast<const float4*>(pb + 3 * O);
        float4 out;
        out.x = a.x * b.x * c.x * d.x;
        out.y = a.y * b.y * c.y * d.y;
        out.z = a.z * b.z * c.z * d.z;
        out.w = a.w * b.w * c.w * d.w;
        *reinterpret_cast<float4*>(
            y + (blockIdx.x * ROWS_PB + r) * O + o4 * 4) = out;
    }
}

extern "C" void kernel_launch(void* const* d_in, const int* in_sizes, int n_in,
                              void* d_out, int out_size, void* d_ws, size_t ws_size,
                              hipStream_t stream) {
    const float* x = (const float*)d_in[0];   // [16384, 256]
    const float* M = (const float*)d_in[1];   // [256, 32]
    float* y = (float*)d_out;                 // [16384, 32]
    const int B = in_sizes[0] / D;            // 16384
    dim3 grid(B / ROWS_PB);                   // 1024 blocks = 4 per CU
    nmu_fwd<<<grid, 256, 0, stream>>>(x, M, y);
}

// Round 9
// 80.104 us; speedup vs baseline: 1.4117x; 1.4117x over previous
//
#include <hip/hip_runtime.h>

// NMU forward: y[b,o] = prod_d( clip(M[d,o],0,1)*x[b,d] + 1-clip(M[d,o],0,1) )
// B=16384, D=256, O=32, fp32.
//
// R9: R8's architecture (broadcast-global x + register-resident M at
// 16 waves/CU), compiled so residency actually happens. R8's VGPR=64 +
// 28 MB WRITE_SIZE showed m[]/buf[] were demoted to scratch. Defenses:
//  - resident M slice = 32 d = 16 v2f = 32 VGPRs (wave owns a 64-d
//    segment; lane = (o, dh) splits it) -> total demand ~95 < 128 cap.
//  - every array index is a compile-time literal: row loop is unroll-1,
//    the two half-row compute blocks are macro-expanded with literal m
//    bases, ping-pong uses two named buffers with no copies.
//  - per row: 8 broadcast float4 loads (VMEM issue ~4cyc, 32 o-lanes share
//    an address), ~50 packed VALU ops against resident m. Zero LDS in the
//    hot loop; per-row partials go to a small padded LDS tile, merged by a
//    128-thread f4-coalesced epilogue.

typedef float v2f __attribute__((ext_vector_type(2)));

constexpr int D = 256;
constexpr int O = 32;
constexpr int SEG = 64;              // d's per wave segment
constexpr int TD  = 32;              // d's per thread
constexpr int ROWS_PB = 16;          // rows per block
constexpr int PSTR = 8 * O + 4;      // 260 floats: 8 sub-segments + pad

// one half-row: 4 float4 from BUF against m[MB..MB+7], folded into p
#define NMU_HALF(BUF, MB)                                                  \
    {                                                                      \
        v2f acc;                                                           \
        _Pragma("unroll")                                                  \
        for (int u = 0; u < 4; ++u) {                                      \
            const float4 xv = BUF[u];                                      \
            v2f x01 = {xv.x - 1.0f, xv.y - 1.0f};                          \
            v2f x23 = {xv.z - 1.0f, xv.w - 1.0f};                          \
            v2f t0 = m[(MB) + 2 * u]     * x01 + (v2f){1.0f, 1.0f};        \
            v2f t1 = m[(MB) + 2 * u + 1] * x23 + (v2f){1.0f, 1.0f};        \
            v2f q = t0 * t1;                                               \
            acc = (u == 0) ? q : acc * q;                                  \
        }                                                                  \
        p *= acc;                                                          \
    }

__global__ __launch_bounds__(256, 4)
void nmu_fwd(const float* __restrict__ x, const float* __restrict__ M,
             float* __restrict__ y)
{
    __shared__ float part[ROWS_PB * PSTR];           // 16.6 KB
    const int tid  = threadIdx.x;
    const int lane = tid & 63;
    const int w    = tid >> 6;                       // wave = d-segment
    const int o    = lane & 31;                      // output column
    const int dh   = lane >> 5;                      // segment half
    const int d0   = w * SEG + dh * TD;              // my 32 d's
    const int row0 = blockIdx.x * ROWS_PB;

    // ---- resident clamped M slice: 16 v2f = 32 VGPRs ----
    v2f m[TD / 2];
    {
        const float* Mp = M + d0 * O + o;
#pragma unroll
        for (int j = 0; j < TD / 2; ++j) {           // coalesced, independent
            float a = Mp[(2 * j    ) * O];
            float b = Mp[(2 * j + 1) * O];
            m[j].x = __builtin_amdgcn_fmed3f(a, 0.0f, 1.0f);
            m[j].y = __builtin_amdgcn_fmed3f(b, 0.0f, 1.0f);
        }
    }

    // x chunks: row r half h -> xg + r*(D/4) + h*4   (4 float4 each)
    const float4* xg = reinterpret_cast<const float4*>(x + row0 * D + d0);

    float4 A[4], Bf[4];                              // named ping-pong
#pragma unroll
    for (int u = 0; u < 4; ++u) A[u] = xg[u];        // prologue: row0 half0

    v2f p = {1.0f, 1.0f};

#pragma unroll 1
    for (int r = 0; r < ROWS_PB; ++r) {
        const float4* xr = xg + r * (D / 4);
#pragma unroll
        for (int u = 0; u < 4; ++u) Bf[u] = xr[4 + u];      // this row half1
        NMU_HALF(A, 0)                                       // compute half0
        if (r + 1 < ROWS_PB) {
#pragma unroll
            for (int u = 0; u < 4; ++u) A[u] = xr[D / 4 + u]; // next row half0
        }
        NMU_HALF(Bf, 8)                                      // compute half1

        part[r * PSTR + (w * 2 + dh) * O + o] = p.x * p.y;   // 2-way alias ok
        p = (v2f){1.0f, 1.0f};
    }
    __syncthreads();

    // ---- merge 8 sub-segment partials, store y ----
    if (tid < ROWS_PB * 8) {                         // 128 threads
        const int r  = tid >> 3;
        const int o4 = tid & 7;
        const float* pb = &part[r * PSTR + o4 * 4];
        float4 acc = *reinterpret_cast<const float4*>(pb);
#pragma unroll
        for (int s = 1; s < 8; ++s) {
            float4 v = *reinterpret_cast<const float4*>(pb + s * O);
            acc.x *= v.x; acc.y *= v.y; acc.z *= v.z; acc.w *= v.w;
        }
        *reinterpret_cast<float4*>(y + (row0 + r) * O + o4 * 4) = acc;
    }
}

extern "C" void kernel_launch(void* const* d_in, const int* in_sizes, int n_in,
                              void* d_out, int out_size, void* d_ws, size_t ws_size,
                              hipStream_t stream) {
    const float* x = (const float*)d_in[0];   // [16384, 256]
    const float* M = (const float*)d_in[1];   // [256, 32]
    float* y = (float*)d_out;                 // [16384, 32]
    const int B = in_sizes[0] / D;            // 16384
    dim3 grid(B / ROWS_PB);                   // 1024 blocks = 4 per CU
    nmu_fwd<<<grid, 256, 0, stream>>>(x, M, y);
}

// Round 11
// 72.744 us; speedup vs baseline: 1.5545x; 1.1012x over previous
//
#include <hip/hip_runtime.h>
#include <stdint.h>

// NMU forward: y[b,o] = prod_d( clip(M[d,o],0,1)*x[b,d] + 1-clip(M[d,o],0,1) )
// B=16384, D=256, O=32, fp32.
//
// R11 = R10 with the DPP control as a template parameter (update_dpp needs
// an immediate). Design recap:
//  - lane = (oq 0..7)*8 + (ds 0..7); wave w owns d-quarter; thread owns
//    8 d's x 4 o's -> resident clamped M = 16 named v2f = 32 VGPRs.
//  - x tile (16 rows x 1 KB) staged per-lane coalesced (R7's staging);
//    compute does only 2 ds_read_b128 per row per wave (4x fewer LDS-port
//    broadcasts than R7 -> port time ~2.6 us instead of ~10).
//  - d-reduction across the 8 ds-lanes via DPP muls (quad_perm xor1, xor2,
//    row_half_mirror) on the VALU pipe - zero LDS traffic.
//  - partials: one b128 write per (row, wave) from ds==0 lanes; merge
//    epilogue multiplies the 4 quarter-partials and stores v2f-coalesced y.

typedef float v2f __attribute__((ext_vector_type(2)));

constexpr int D = 256;
constexpr int O = 32;
constexpr int ROWS_PB = 16;              // rows per block -> 1024 blocks

template <int CTRL>
__device__ __forceinline__ float dppmul(float v) {
    int i = __builtin_bit_cast(int, v);
    int p = __builtin_amdgcn_update_dpp(i, i, CTRL, 0xF, 0xF, false);
    return v * __builtin_bit_cast(float, p);
}
template <int CTRL>
__device__ __forceinline__ v2f dppmul2(v2f v) {
    v2f r; r.x = dppmul<CTRL>(v.x); r.y = dppmul<CTRL>(v.y); return r;
}
__device__ __forceinline__ v2f clamp01(v2f v) {
    v = __builtin_elementwise_max(v, (v2f)0.0f);
    return __builtin_elementwise_min(v, (v2f)1.0f);
}
// t = m*(x-1)+1  ==  m*x + (1-m)
#define TERM(mm, e) __builtin_elementwise_fma((mm), (v2f){(e), (e)}, (v2f){1.0f, 1.0f})

__global__ __launch_bounds__(256, 4)
void nmu_fwd(const float* __restrict__ x, const float* __restrict__ M,
             float* __restrict__ y)
{
    __shared__ __align__(16) float xt[ROWS_PB * D];          // 16 KB x tile
    __shared__ __align__(16) float part[ROWS_PB * 4 * O];    // 8 KB partials
    const int tid  = threadIdx.x;
    const int lane = tid & 63;
    const int w    = tid >> 6;       // wave = d-quarter
    const int ds   = lane & 7;       // 8-d subslice (low bits -> DPP groups)
    const int oq   = lane >> 3;      // o-quad
    const int row0 = blockIdx.x * ROWS_PB;

    // ---- stage x tile: 4 independent 1KB-coalesced f4 loads per thread ----
    const float4* xg = reinterpret_cast<const float4*>(x + row0 * D);
    float4 s0 = xg[tid], s1 = xg[256 + tid], s2 = xg[512 + tid], s3 = xg[768 + tid];

    // ---- resident clamped M slice: d = w*64+ds*8+dd, o = oq*4..oq*4+3 ----
    const float2* M2 = reinterpret_cast<const float2*>(M);
    const int mb = (w * 64 + ds * 8) * (O / 2) + oq * 2;     // float2 index
#define MLOAD(dd) \
    float2 l##dd = M2[mb + (dd) * 16]; float2 h##dd = M2[mb + (dd) * 16 + 1]; \
    v2f mL##dd = clamp01((v2f){l##dd.x, l##dd.y});                            \
    v2f mH##dd = clamp01((v2f){h##dd.x, h##dd.y});
    MLOAD(0) MLOAD(1) MLOAD(2) MLOAD(3) MLOAD(4) MLOAD(5) MLOAD(6) MLOAD(7)
#undef MLOAD

    float4* lp = reinterpret_cast<float4*>(xt);
    lp[tid] = s0; lp[256 + tid] = s1; lp[512 + tid] = s2; lp[768 + tid] = s3;
    __syncthreads();

    // ---- per row: 2 ds_read_b128, 8 d-terms x 4 o, DPP reduce, write ----
    const int xoff = w * 16 + ds * 2;                        // f4 idx in row
    const float4* lt = reinterpret_cast<const float4*>(xt);
#pragma unroll 1
    for (int r = 0; r < ROWS_PB; ++r) {
        const float4 xa = lt[r * 64 + xoff];
        const float4 xb = lt[r * 64 + xoff + 1];
        const float e0 = xa.x - 1.0f, e1 = xa.y - 1.0f;
        const float e2 = xa.z - 1.0f, e3 = xa.w - 1.0f;
        const float e4 = xb.x - 1.0f, e5 = xb.y - 1.0f;
        const float e6 = xb.z - 1.0f, e7 = xb.w - 1.0f;

        v2f pL = (TERM(mL0, e0) * TERM(mL1, e1)) * (TERM(mL2, e2) * TERM(mL3, e3));
        pL    *= (TERM(mL4, e4) * TERM(mL5, e5)) * (TERM(mL6, e6) * TERM(mL7, e7));
        v2f pH = (TERM(mH0, e0) * TERM(mH1, e1)) * (TERM(mH2, e2) * TERM(mH3, e3));
        pH    *= (TERM(mH4, e4) * TERM(mH5, e5)) * (TERM(mH6, e6) * TERM(mH7, e7));

        // product across the 8 ds-lanes: xor1, xor2, then row-half mirror
        pL = dppmul2<0xB1>(pL); pL = dppmul2<0x4E>(pL); pL = dppmul2<0x141>(pL);
        pH = dppmul2<0xB1>(pH); pH = dppmul2<0x4E>(pH); pH = dppmul2<0x141>(pH);

        if (ds == 0) {                                       // 8 lanes/wave
            float4 pv = {pL.x, pL.y, pH.x, pH.y};
            *reinterpret_cast<float4*>(&part[(r * 4 + w) * O + oq * 4]) = pv;
        }
    }
    __syncthreads();

    // ---- merge 4 quarter-partials; 256 threads = 16 rows x 16 o-pairs ----
    {
        const int mr = tid >> 4;
        const int op = tid & 15;
        const v2f* pp = reinterpret_cast<const v2f*>(part);
        v2f a = pp[(mr * 4 + 0) * (O / 2) + op] * pp[(mr * 4 + 1) * (O / 2) + op];
        v2f b = pp[(mr * 4 + 2) * (O / 2) + op] * pp[(mr * 4 + 3) * (O / 2) + op];
        a *= b;
        *reinterpret_cast<v2f*>(y + (row0 + mr) * O + op * 2) = a;  // 8B/lane
    }
}

extern "C" void kernel_launch(void* const* d_in, const int* in_sizes, int n_in,
                              void* d_out, int out_size, void* d_ws, size_t ws_size,
                              hipStream_t stream) {
    const float* x = (const float*)d_in[0];   // [16384, 256]
    const float* M = (const float*)d_in[1];   // [256, 32]
    float* y = (float*)d_out;                 // [16384, 32]
    const int B = in_sizes[0] / D;            // 16384
    dim3 grid(B / ROWS_PB);                   // 1024 blocks = 4 per CU
    nmu_fwd<<<grid, 256, 0, stream>>>(x, M, y);
}